// Round 1
// baseline (660.624 us; speedup 1.0000x reference)
//
#include <hip/hip_runtime.h>
#include <hip/hip_bf16.h>

#define N_NODES 50000
#define N_EDGES 500000
#define D 256
#define K_TOT 768      // 3 * D
#define M_TILE 128
#define N_TILE 128
#define LDT 56         // LDS pitch in bf16: 112B = 28 banks -> 2-way (free) on frag reads, 16B-aligned

typedef __attribute__((ext_vector_type(8))) __bf16 bf16x8;
typedef __attribute__((ext_vector_type(4))) float f32x4;

__device__ __forceinline__ unsigned short f2bf(float f) {
    unsigned u = __builtin_bit_cast(unsigned, f);
    u += 0x7FFFu + ((u >> 16) & 1u);   // round-to-nearest-even
    return (unsigned short)(u >> 16);
}

// ---------------- CSR build ----------------

__global__ void count_kernel(const int* __restrict__ d0, const int* __restrict__ d1,
                             const int* __restrict__ d2, int* __restrict__ cnt) {
    int i = blockIdx.x * blockDim.x + threadIdx.x;
    if (i >= 3 * N_EDGES) return;
    int r = i / N_EDGES;
    int e = i - r * N_EDGES;
    const int* d = (r == 0) ? d0 : (r == 1) ? d1 : d2;
    atomicAdd(&cnt[r * N_NODES + d[e]], 1);
}

// single-block exclusive scan over cnt[3*N_NODES] -> off, cur
__global__ void scan_kernel(const int* __restrict__ cnt, int* __restrict__ off,
                            int* __restrict__ cur, int total) {
    __shared__ int warp_sums[16];
    __shared__ int carry_s;
    int tid = threadIdx.x;           // 1024 threads
    int lane = tid & 63, wid = tid >> 6;
    if (tid == 0) carry_s = 0;
    __syncthreads();
    for (int base = 0; base < total; base += 1024) {
        int i = base + tid;
        int v = (i < total) ? cnt[i] : 0;
        int x = v;
        #pragma unroll
        for (int dlt = 1; dlt < 64; dlt <<= 1) {
            int y = __shfl_up(x, dlt, 64);
            if (lane >= dlt) x += y;
        }
        if (lane == 63) warp_sums[wid] = x;
        __syncthreads();
        if (wid == 0 && lane < 16) {
            int s = warp_sums[lane];
            #pragma unroll
            for (int dlt = 1; dlt < 16; dlt <<= 1) {
                int y = __shfl_up(s, dlt, 64);
                if (lane >= dlt) s += y;
            }
            warp_sums[lane] = s;
        }
        __syncthreads();
        int wprefix = (wid > 0) ? warp_sums[wid - 1] : 0;
        int incl = x + wprefix + carry_s;
        int excl = incl - v;
        if (i < total) { off[i] = excl; cur[i] = excl; }
        __syncthreads();                    // everyone done reading carry_s / warp_sums
        if (tid == 1023) carry_s = incl;    // block total (chunk sum + old carry)
        __syncthreads();
    }
}

__global__ void fill_kernel(const int* __restrict__ s0, const int* __restrict__ d0,
                            const int* __restrict__ s1, const int* __restrict__ d1,
                            const int* __restrict__ s2, const int* __restrict__ d2,
                            int* __restrict__ cur, int* __restrict__ eidx) {
    int i = blockIdx.x * blockDim.x + threadIdx.x;
    if (i >= 3 * N_EDGES) return;
    int r = i / N_EDGES;
    int e = i - r * N_EDGES;
    const int* s = (r == 0) ? s0 : (r == 1) ? s1 : s2;
    const int* d = (r == 0) ? d0 : (r == 1) ? d1 : d2;
    int p = atomicAdd(&cur[r * N_NODES + d[e]], 1);
    eidx[p] = s[e];
}

// ---------------- per-(relation,node) mean aggregation of raw features ----------------
// one wave per (r,n); each lane owns 4 consecutive channels (float4)
// writes agg as bf16, layout [node][relation][256]  => row-major [N_NODES][768]
__global__ void agg_kernel(const float* __restrict__ feat, const int* __restrict__ off,
                           const int* __restrict__ cur, const int* __restrict__ eidx,
                           unsigned short* __restrict__ agg) {
    int wid = (blockIdx.x * blockDim.x + threadIdx.x) >> 6;
    int lane = threadIdx.x & 63;
    if (wid >= 3 * N_NODES) return;
    int r = wid / N_NODES;
    int n = wid - r * N_NODES;
    int start = off[wid], end = cur[wid];
    float4 acc = make_float4(0.f, 0.f, 0.f, 0.f);
    for (int i = start; i < end; ++i) {
        int s = eidx[i];
        float4 v = *((const float4*)(feat + (size_t)s * D) + lane);
        acc.x += v.x; acc.y += v.y; acc.z += v.z; acc.w += v.w;
    }
    int deg = end - start;
    float sc = (deg > 0) ? 1.0f / (float)deg : 0.0f;
    ushort4 pk;
    pk.x = f2bf(acc.x * sc);
    pk.y = f2bf(acc.y * sc);
    pk.z = f2bf(acc.z * sc);
    pk.w = f2bf(acc.w * sc);
    *(ushort4*)(agg + (((size_t)n * 3 + r) * D) + lane * 4) = pk;
}

// ---------------- W -> bf16, transposed: WT[c][k], k = r*256+kin, WT[c][k] = W_r[kin][c] ----------------
__global__ void wconv_kernel(const float* __restrict__ W0, const float* __restrict__ W1,
                             const float* __restrict__ W2, unsigned short* __restrict__ WT) {
    int t = blockIdx.x * blockDim.x + threadIdx.x;
    if (t >= D * K_TOT) return;
    int c = t / K_TOT;
    int k = t - c * K_TOT;
    int r = k >> 8, kin = k & 255;
    const float* W = (r == 0) ? W0 : (r == 1) ? W1 : W2;
    WT[t] = f2bf(W[kin * D + c]);
}

// ---------------- fused GEMM: out = relu( A[50000][768] @ B[768][256] + masked biases ) ----------------
// A = agg (bf16 row-major), B given transposed as WT[256][768]
__global__ __launch_bounds__(256) void gemm_kernel(
    const unsigned short* __restrict__ A, const unsigned short* __restrict__ BT,
    const int* __restrict__ cnt,
    const float* __restrict__ b0, const float* __restrict__ b1, const float* __restrict__ b2,
    float* __restrict__ out) {
    __shared__ __bf16 Asl[M_TILE][LDT];
    __shared__ __bf16 Bsl[N_TILE][LDT];
    int tid = threadIdx.x;
    int lane = tid & 63, w = tid >> 6;
    int wr = w >> 1, wc = w & 1;
    int m0 = blockIdx.y * M_TILE;
    int c0 = blockIdx.x * N_TILE;
    f32x4 acc[4][4] = {};

    for (int kt = 0; kt < K_TOT / 32; ++kt) {
        // stage A tile 128x32 (bf16), 512 16B loads
        #pragma unroll
        for (int L = tid; L < 512; L += 256) {
            int row = L >> 2, seg = L & 3;
            int gm = m0 + row;
            uint4 v = make_uint4(0u, 0u, 0u, 0u);
            if (gm < N_NODES)
                v = *(const uint4*)(A + (size_t)gm * K_TOT + kt * 32 + seg * 8);
            *(uint4*)&Asl[row][seg * 8] = v;
        }
        // stage B tile (cols of out = rows of BT) 128x32
        #pragma unroll
        for (int L = tid; L < 512; L += 256) {
            int row = L >> 2, seg = L & 3;
            uint4 v = *(const uint4*)(BT + (size_t)(c0 + row) * K_TOT + kt * 32 + seg * 8);
            *(uint4*)&Bsl[row][seg * 8] = v;
        }
        __syncthreads();
        int kq = (lane >> 4) * 8;
        bf16x8 af[4], bfr[4];
        #pragma unroll
        for (int mf = 0; mf < 4; ++mf)
            af[mf] = *(const bf16x8*)&Asl[wr * 64 + mf * 16 + (lane & 15)][kq];
        #pragma unroll
        for (int nf = 0; nf < 4; ++nf)
            bfr[nf] = *(const bf16x8*)&Bsl[wc * 64 + nf * 16 + (lane & 15)][kq];
        #pragma unroll
        for (int mf = 0; mf < 4; ++mf)
            #pragma unroll
            for (int nf = 0; nf < 4; ++nf)
                acc[mf][nf] = __builtin_amdgcn_mfma_f32_16x16x32_bf16(af[mf], bfr[nf], acc[mf][nf], 0, 0, 0);
        __syncthreads();
    }

    // epilogue: masked biases + relu; C/D layout: col = lane&15, row = (lane>>4)*4 + reg
    #pragma unroll
    for (int mf = 0; mf < 4; ++mf) {
        #pragma unroll
        for (int nf = 0; nf < 4; ++nf) {
            int col = c0 + wc * 64 + nf * 16 + (lane & 15);
            #pragma unroll
            for (int reg = 0; reg < 4; ++reg) {
                int row = m0 + wr * 64 + mf * 16 + ((lane >> 4) * 4) + reg;
                if (row < N_NODES) {
                    float v = acc[mf][nf][reg];
                    if (cnt[row] > 0)               v += b0[col];
                    if (cnt[N_NODES + row] > 0)     v += b1[col];
                    if (cnt[2 * N_NODES + row] > 0) v += b2[col];
                    out[(size_t)row * D + col] = fmaxf(v, 0.0f);
                }
            }
        }
    }
}

extern "C" void kernel_launch(void* const* d_in, const int* in_sizes, int n_in,
                              void* d_out, int out_size, void* d_ws, size_t ws_size,
                              hipStream_t stream) {
    const float* feat = (const float*)d_in[0];
    const int* src0 = (const int*)d_in[1];
    const int* dst0 = (const int*)d_in[2];
    const int* src1 = (const int*)d_in[3];
    const int* dst1 = (const int*)d_in[4];
    const int* src2 = (const int*)d_in[5];
    const int* dst2 = (const int*)d_in[6];
    const float* W0 = (const float*)d_in[7];
    const float* b0 = (const float*)d_in[8];
    const float* W1 = (const float*)d_in[9];
    const float* b1 = (const float*)d_in[10];
    const float* W2 = (const float*)d_in[11];
    const float* b2 = (const float*)d_in[12];
    float* out = (float*)d_out;

    char* ws = (char*)d_ws;
    size_t o = 0;
    auto alloc = [&](size_t bytes) {
        size_t r = o;
        o += (bytes + 255) & ~(size_t)255;
        return r;
    };
    int* cnt            = (int*)(ws + alloc(3ull * N_NODES * 4));
    int* off            = (int*)(ws + alloc(3ull * N_NODES * 4));
    int* cur            = (int*)(ws + alloc(3ull * N_NODES * 4));
    int* eidx           = (int*)(ws + alloc(3ull * N_EDGES * 4));
    unsigned short* WT  = (unsigned short*)(ws + alloc((size_t)D * K_TOT * 2));
    unsigned short* agg = (unsigned short*)(ws + alloc(3ull * N_NODES * D * 2));

    hipMemsetAsync(cnt, 0, 3ull * N_NODES * 4, stream);
    wconv_kernel<<<(D * K_TOT + 255) / 256, 256, 0, stream>>>(W0, W1, W2, WT);
    count_kernel<<<(3 * N_EDGES + 255) / 256, 256, 0, stream>>>(dst0, dst1, dst2, cnt);
    scan_kernel<<<1, 1024, 0, stream>>>(cnt, off, cur, 3 * N_NODES);
    fill_kernel<<<(3 * N_EDGES + 255) / 256, 256, 0, stream>>>(src0, dst0, src1, dst1, src2, dst2, cur, eidx);
    agg_kernel<<<(3 * N_NODES * 64) / 256, 256, 0, stream>>>(feat, off, cur, eidx, agg);
    dim3 g(D / N_TILE, (N_NODES + M_TILE - 1) / M_TILE);
    gemm_kernel<<<g, 256, 0, stream>>>(agg, WT, cnt, b0, b1, b2, out);
}

// Round 2
// 429.691 us; speedup vs baseline: 1.5374x; 1.5374x over previous
//
#include <hip/hip_runtime.h>
#include <hip/hip_bf16.h>

#define N_NODES 50000
#define N_EDGES 500000
#define D 256
#define K_TOT 768      // 3 * D
#define M_TILE 128
#define N_TILE 128
#define BK 32
#define SCAN_N (3 * N_NODES)
#define SCAN_NBLK ((SCAN_N + 1023) / 1024)   // 147

typedef __attribute__((ext_vector_type(8))) __bf16 bf16x8;
typedef __attribute__((ext_vector_type(4))) float f32x4;

__device__ __forceinline__ unsigned short f2bf(float f) {
    unsigned u = __builtin_bit_cast(unsigned, f);
    u += 0x7FFFu + ((u >> 16) & 1u);   // round-to-nearest-even
    return (unsigned short)(u >> 16);
}
__device__ __forceinline__ float bf2f(unsigned short h) {
    return __builtin_bit_cast(float, (unsigned)h << 16);
}
__device__ __forceinline__ void gload16(const unsigned short* g, __bf16* l) {
    __builtin_amdgcn_global_load_lds(
        (const __attribute__((address_space(1))) void*)g,
        (__attribute__((address_space(3))) void*)l, 16, 0, 0);
}

// ---------------- features f32 -> bf16 ----------------
__global__ void f2b_kernel(const float* __restrict__ feat, unsigned short* __restrict__ fb) {
    int i = blockIdx.x * blockDim.x + threadIdx.x;   // over N_NODES*D/4
    float4 v = ((const float4*)feat)[i];
    ushort4 pk;
    pk.x = f2bf(v.x); pk.y = f2bf(v.y); pk.z = f2bf(v.z); pk.w = f2bf(v.w);
    ((ushort4*)fb)[i] = pk;
}

// ---------------- CSR build ----------------
__global__ void count_kernel(const int* __restrict__ d0, const int* __restrict__ d1,
                             const int* __restrict__ d2, int* __restrict__ cnt) {
    int i = blockIdx.x * blockDim.x + threadIdx.x;
    if (i >= 3 * N_EDGES) return;
    int r = i / N_EDGES;
    int e = i - r * N_EDGES;
    const int* d = (r == 0) ? d0 : (r == 1) ? d1 : d2;
    atomicAdd(&cnt[r * N_NODES + d[e]], 1);
}

// hierarchical scan: per-block exclusive scan + block sums
__global__ void scan1_kernel(const int* __restrict__ cnt, int* __restrict__ off,
                             int* __restrict__ bsum) {
    __shared__ int wsum[16];
    int tid = threadIdx.x, lane = tid & 63, wid = tid >> 6;
    int i = blockIdx.x * 1024 + tid;
    int v = (i < SCAN_N) ? cnt[i] : 0;
    int x = v;
    #pragma unroll
    for (int d = 1; d < 64; d <<= 1) {
        int y = __shfl_up(x, d, 64);
        if (lane >= d) x += y;
    }
    if (lane == 63) wsum[wid] = x;
    __syncthreads();
    if (wid == 0 && lane < 16) {
        int s = wsum[lane];
        #pragma unroll
        for (int d = 1; d < 16; d <<= 1) {
            int y = __shfl_up(s, d, 64);
            if (lane >= d) s += y;
        }
        wsum[lane] = s;
    }
    __syncthreads();
    int wpre = wid ? wsum[wid - 1] : 0;
    int excl = x - v + wpre;
    if (i < SCAN_N) off[i] = excl;
    if (tid == 1023) bsum[blockIdx.x] = x + wpre;   // block total
}

// exclusive scan of the 147 block sums (single block)
__global__ void scan2_kernel(int* __restrict__ bsum) {
    __shared__ int wsum[16];
    int tid = threadIdx.x, lane = tid & 63, wid = tid >> 6;
    int v = (tid < SCAN_NBLK) ? bsum[tid] : 0;
    int x = v;
    #pragma unroll
    for (int d = 1; d < 64; d <<= 1) {
        int y = __shfl_up(x, d, 64);
        if (lane >= d) x += y;
    }
    if (lane == 63) wsum[wid] = x;
    __syncthreads();
    if (wid == 0 && lane < 16) {
        int s = wsum[lane];
        #pragma unroll
        for (int d = 1; d < 16; d <<= 1) {
            int y = __shfl_up(s, d, 64);
            if (lane >= d) s += y;
        }
        wsum[lane] = s;
    }
    __syncthreads();
    int wpre = wid ? wsum[wid - 1] : 0;
    if (tid < SCAN_NBLK) bsum[tid] = x - v + wpre;
}

__global__ void scan3_kernel(int* __restrict__ off, int* __restrict__ cur,
                             const int* __restrict__ bsum) {
    int i = blockIdx.x * 1024 + threadIdx.x;
    if (i >= SCAN_N) return;
    int v = off[i] + bsum[blockIdx.x];
    off[i] = v;
    cur[i] = v;
}

__global__ void fill_kernel(const int* __restrict__ s0, const int* __restrict__ d0,
                            const int* __restrict__ s1, const int* __restrict__ d1,
                            const int* __restrict__ s2, const int* __restrict__ d2,
                            int* __restrict__ cur, int* __restrict__ eidx) {
    int i = blockIdx.x * blockDim.x + threadIdx.x;
    if (i >= 3 * N_EDGES) return;
    int r = i / N_EDGES;
    int e = i - r * N_EDGES;
    const int* s = (r == 0) ? s0 : (r == 1) ? s1 : s2;
    const int* d = (r == 0) ? d0 : (r == 1) ? d1 : d2;
    int p = atomicAdd(&cur[r * N_NODES + d[e]], 1);
    eidx[p] = s[e];
}

// ---------------- per-(relation,node) mean aggregation of bf16 features ----------------
// one wave per (r,n); lane owns 4 consecutive channels (ushort4 = 8B)
// writes agg layout [node][relation][256] => row-major [N_NODES][768]
__global__ void agg_kernel(const unsigned short* __restrict__ fb, const int* __restrict__ off,
                           const int* __restrict__ cur, const int* __restrict__ eidx,
                           unsigned short* __restrict__ agg) {
    int wid = (blockIdx.x * blockDim.x + threadIdx.x) >> 6;
    int lane = threadIdx.x & 63;
    if (wid >= 3 * N_NODES) return;
    int r = wid / N_NODES;
    int n = wid - r * N_NODES;
    int start = off[wid], end = cur[wid];
    float4 acc = make_float4(0.f, 0.f, 0.f, 0.f);
    int i = start;
    for (; i + 1 < end; i += 2) {           // 2 independent gathers in flight
        int s0 = eidx[i], s1 = eidx[i + 1];
        ushort4 v0 = *(const ushort4*)(fb + (size_t)s0 * D + lane * 4);
        ushort4 v1 = *(const ushort4*)(fb + (size_t)s1 * D + lane * 4);
        acc.x += bf2f(v0.x) + bf2f(v1.x);
        acc.y += bf2f(v0.y) + bf2f(v1.y);
        acc.z += bf2f(v0.z) + bf2f(v1.z);
        acc.w += bf2f(v0.w) + bf2f(v1.w);
    }
    if (i < end) {
        ushort4 v = *(const ushort4*)(fb + (size_t)eidx[i] * D + lane * 4);
        acc.x += bf2f(v.x); acc.y += bf2f(v.y); acc.z += bf2f(v.z); acc.w += bf2f(v.w);
    }
    int deg = end - start;
    float sc = (deg > 0) ? 1.0f / (float)deg : 0.0f;
    ushort4 pk;
    pk.x = f2bf(acc.x * sc);
    pk.y = f2bf(acc.y * sc);
    pk.z = f2bf(acc.z * sc);
    pk.w = f2bf(acc.w * sc);
    *(ushort4*)(agg + (((size_t)n * 3 + r) * D) + lane * 4) = pk;
}

// ---------------- W -> bf16, transposed: WT[c][k], k = r*256+kin ----------------
__global__ void wconv_kernel(const float* __restrict__ W0, const float* __restrict__ W1,
                             const float* __restrict__ W2, unsigned short* __restrict__ WT) {
    int t = blockIdx.x * blockDim.x + threadIdx.x;
    if (t >= D * K_TOT) return;
    int c = t / K_TOT;
    int k = t - c * K_TOT;
    int r = k >> 8, kin = k & 255;
    const float* W = (r == 0) ? W0 : (r == 1) ? W1 : W2;
    WT[t] = f2bf(W[kin * D + c]);
}

// ---------------- fused GEMM: out = relu( A[50000][768] @ B[768][256] + masked biases ) ----------------
// A = agg (bf16 row-major), B given transposed as WT[256][768]
// m97 structure: linear [128][32] LDS tiles + global_load_lds width=16
__global__ __launch_bounds__(256) void gemm_kernel(
    const unsigned short* __restrict__ A, const unsigned short* __restrict__ BT,
    const int* __restrict__ cnt,
    const float* __restrict__ b0, const float* __restrict__ b1, const float* __restrict__ b2,
    float* __restrict__ out) {
    __shared__ __bf16 Asl[M_TILE][BK];   // 8 KB, linear (gload_lds writes base+lane*16)
    __shared__ __bf16 Bsl[N_TILE][BK];   // 8 KB
    int tid = threadIdx.x;
    int lane = tid & 63, w = tid >> 6;
    int wr = w >> 1, wc = w & 1;
    int m0 = blockIdx.y * M_TILE;
    int c0 = blockIdx.x * N_TILE;
    f32x4 acc[4][4] = {};

    for (int kt = 0; kt < K_TOT / BK; ++kt) {
        #pragma unroll
        for (int it = 0; it < 2; ++it) {
            int s = it * 256 + w * 64 + lane;      // flat 16B slot 0..511
            int row = s >> 2, seg = s & 3;
            // A tile: clamp M-tail rows to a valid address (results discarded in epilogue)
            int gm = m0 + row; if (gm >= N_NODES) gm = N_NODES - 1;
            gload16(A + (size_t)gm * K_TOT + kt * BK + seg * 8,
                    &Asl[0][0] + (size_t)(it * 256 + w * 64) * 8);
            gload16(BT + (size_t)(c0 + row) * K_TOT + kt * BK + seg * 8,
                    &Bsl[0][0] + (size_t)(it * 256 + w * 64) * 8);
        }
        __syncthreads();
        int kq = (lane >> 4) * 8;
        bf16x8 af[4], bfr[4];
        #pragma unroll
        for (int mf = 0; mf < 4; ++mf)
            af[mf] = *(const bf16x8*)&Asl[wr * 64 + mf * 16 + (lane & 15)][kq];
        #pragma unroll
        for (int nf = 0; nf < 4; ++nf)
            bfr[nf] = *(const bf16x8*)&Bsl[wc * 64 + nf * 16 + (lane & 15)][kq];
        #pragma unroll
        for (int mf = 0; mf < 4; ++mf)
            #pragma unroll
            for (int nf = 0; nf < 4; ++nf)
                acc[mf][nf] = __builtin_amdgcn_mfma_f32_16x16x32_bf16(af[mf], bfr[nf], acc[mf][nf], 0, 0, 0);
        __syncthreads();
    }

    // epilogue: masked biases + relu; C/D layout: col = lane&15, row = (lane>>4)*4 + reg
    #pragma unroll
    for (int mf = 0; mf < 4; ++mf) {
        #pragma unroll
        for (int nf = 0; nf < 4; ++nf) {
            int col = c0 + wc * 64 + nf * 16 + (lane & 15);
            #pragma unroll
            for (int reg = 0; reg < 4; ++reg) {
                int row = m0 + wr * 64 + mf * 16 + ((lane >> 4) * 4) + reg;
                if (row < N_NODES) {
                    float v = acc[mf][nf][reg];
                    if (cnt[row] > 0)               v += b0[col];
                    if (cnt[N_NODES + row] > 0)     v += b1[col];
                    if (cnt[2 * N_NODES + row] > 0) v += b2[col];
                    out[(size_t)row * D + col] = fmaxf(v, 0.0f);
                }
            }
        }
    }
}

extern "C" void kernel_launch(void* const* d_in, const int* in_sizes, int n_in,
                              void* d_out, int out_size, void* d_ws, size_t ws_size,
                              hipStream_t stream) {
    const float* feat = (const float*)d_in[0];
    const int* src0 = (const int*)d_in[1];
    const int* dst0 = (const int*)d_in[2];
    const int* src1 = (const int*)d_in[3];
    const int* dst1 = (const int*)d_in[4];
    const int* src2 = (const int*)d_in[5];
    const int* dst2 = (const int*)d_in[6];
    const float* W0 = (const float*)d_in[7];
    const float* b0 = (const float*)d_in[8];
    const float* W1 = (const float*)d_in[9];
    const float* b1 = (const float*)d_in[10];
    const float* W2 = (const float*)d_in[11];
    const float* b2 = (const float*)d_in[12];
    float* out = (float*)d_out;

    char* ws = (char*)d_ws;
    size_t o = 0;
    auto alloc = [&](size_t bytes) {
        size_t r = o;
        o += (bytes + 255) & ~(size_t)255;
        return r;
    };
    int* cnt            = (int*)(ws + alloc(3ull * N_NODES * 4));
    int* off            = (int*)(ws + alloc(3ull * N_NODES * 4));
    int* cur            = (int*)(ws + alloc(3ull * N_NODES * 4));
    int* bsum           = (int*)(ws + alloc((size_t)SCAN_NBLK * 4));
    int* eidx           = (int*)(ws + alloc(3ull * N_EDGES * 4));
    unsigned short* WT  = (unsigned short*)(ws + alloc((size_t)D * K_TOT * 2));
    unsigned short* fb  = (unsigned short*)(ws + alloc((size_t)N_NODES * D * 2));
    unsigned short* agg = (unsigned short*)(ws + alloc(3ull * N_NODES * D * 2));

    hipMemsetAsync(cnt, 0, 3ull * N_NODES * 4, stream);
    wconv_kernel<<<(D * K_TOT + 255) / 256, 256, 0, stream>>>(W0, W1, W2, WT);
    f2b_kernel<<<(N_NODES * D / 4 + 255) / 256, 256, 0, stream>>>(feat, fb);
    count_kernel<<<(3 * N_EDGES + 255) / 256, 256, 0, stream>>>(dst0, dst1, dst2, cnt);
    scan1_kernel<<<SCAN_NBLK, 1024, 0, stream>>>(cnt, off, bsum);
    scan2_kernel<<<1, 1024, 0, stream>>>(bsum);
    scan3_kernel<<<SCAN_NBLK, 1024, 0, stream>>>(off, cur, bsum);
    fill_kernel<<<(3 * N_EDGES + 255) / 256, 256, 0, stream>>>(src0, dst0, src1, dst1, src2, dst2, cur, eidx);
    agg_kernel<<<(3 * N_NODES * 64) / 256, 256, 0, stream>>>(fb, off, cur, eidx, agg);
    dim3 g(D / N_TILE, (N_NODES + M_TILE - 1) / M_TILE);
    gemm_kernel<<<g, 256, 0, stream>>>(agg, WT, cnt, b0, b1, b2, out);
}

// Round 3
// 386.271 us; speedup vs baseline: 1.7103x; 1.1124x over previous
//
#include <hip/hip_runtime.h>
#include <hip/hip_bf16.h>

#define N_NODES 50000
#define N_EDGES 500000
#define D 256
#define K_TOT 768      // 3 * D
#define M_TILE 128
#define N_TILE 128
#define BK 32
#define NKT (K_TOT / BK)                     // 24
#define SCAN_N (3 * N_NODES)
#define SCAN_NBLK ((SCAN_N + 1023) / 1024)   // 147

typedef __attribute__((ext_vector_type(8))) __bf16 bf16x8;
typedef __attribute__((ext_vector_type(4))) float f32x4;

__device__ __forceinline__ unsigned short f2bf(float f) {
    unsigned u = __builtin_bit_cast(unsigned, f);
    u += 0x7FFFu + ((u >> 16) & 1u);   // round-to-nearest-even
    return (unsigned short)(u >> 16);
}
__device__ __forceinline__ float bf2f(unsigned short h) {
    return __builtin_bit_cast(float, (unsigned)h << 16);
}
__device__ __forceinline__ void gload16(const unsigned short* g, __bf16* l) {
    __builtin_amdgcn_global_load_lds(
        (const __attribute__((address_space(1))) void*)g,
        (__attribute__((address_space(3))) void*)l, 16, 0, 0);
}

// ---------------- prep: zero cnt + W->bf16 transposed + feat->bf16 ----------------
__global__ void prep_kernel(const float* __restrict__ feat, unsigned short* __restrict__ fb,
                            const float* __restrict__ W0, const float* __restrict__ W1,
                            const float* __restrict__ W2, unsigned short* __restrict__ WT,
                            int* __restrict__ cnt) {
    int i = blockIdx.x * blockDim.x + threadIdx.x;
    if (i < N_NODES * D / 4) {                       // 3.2M float4 slots
        float4 v = ((const float4*)feat)[i];
        ushort4 pk;
        pk.x = f2bf(v.x); pk.y = f2bf(v.y); pk.z = f2bf(v.z); pk.w = f2bf(v.w);
        ((ushort4*)fb)[i] = pk;
    }
    if (i < D * K_TOT) {                             // WT[c][k], k = r*256+kin
        int c = i / K_TOT;
        int k = i - c * K_TOT;
        int r = k >> 8, kin = k & 255;
        const float* W = (r == 0) ? W0 : (r == 1) ? W1 : W2;
        WT[i] = f2bf(W[kin * D + c]);
    }
    if (i < SCAN_N / 4 + 1) {                        // zero cnt (150000 ints)
        if (i * 4 + 3 < SCAN_N) ((int4*)cnt)[i] = make_int4(0, 0, 0, 0);
        else for (int j = i * 4; j < SCAN_N; ++j) cnt[j] = 0;
    }
}

// ---------------- CSR build ----------------
__global__ void count_kernel(const int* __restrict__ d0, const int* __restrict__ d1,
                             const int* __restrict__ d2, int* __restrict__ cnt) {
    int i = blockIdx.x * blockDim.x + threadIdx.x;
    if (i >= 3 * N_EDGES) return;
    int r = i / N_EDGES;
    int e = i - r * N_EDGES;
    const int* d = (r == 0) ? d0 : (r == 1) ? d1 : d2;
    atomicAdd(&cnt[r * N_NODES + d[e]], 1);
}

// per-block exclusive scan; off/cur hold BLOCK-LOCAL offsets, bsum holds block totals
__global__ void scan1_kernel(const int* __restrict__ cnt, int* __restrict__ off,
                             int* __restrict__ cur, int* __restrict__ bsum) {
    __shared__ int wsum[16];
    int tid = threadIdx.x, lane = tid & 63, wid = tid >> 6;
    int i = blockIdx.x * 1024 + tid;
    int v = (i < SCAN_N) ? cnt[i] : 0;
    int x = v;
    #pragma unroll
    for (int d = 1; d < 64; d <<= 1) {
        int y = __shfl_up(x, d, 64);
        if (lane >= d) x += y;
    }
    if (lane == 63) wsum[wid] = x;
    __syncthreads();
    if (wid == 0 && lane < 16) {
        int s = wsum[lane];
        #pragma unroll
        for (int d = 1; d < 16; d <<= 1) {
            int y = __shfl_up(s, d, 64);
            if (lane >= d) s += y;
        }
        wsum[lane] = s;
    }
    __syncthreads();
    int wpre = wid ? wsum[wid - 1] : 0;
    int excl = x - v + wpre;
    if (i < SCAN_N) { off[i] = excl; cur[i] = excl; }
    if (tid == 1023) bsum[blockIdx.x] = x + wpre;
}

// exclusive scan of the 147 block sums (single block, in place)
__global__ void scan2_kernel(int* __restrict__ bsum) {
    __shared__ int wsum[16];
    int tid = threadIdx.x, lane = tid & 63, wid = tid >> 6;
    int v = (tid < SCAN_NBLK) ? bsum[tid] : 0;
    int x = v;
    #pragma unroll
    for (int d = 1; d < 64; d <<= 1) {
        int y = __shfl_up(x, d, 64);
        if (lane >= d) x += y;
    }
    if (lane == 63) wsum[wid] = x;
    __syncthreads();
    if (wid == 0 && lane < 16) {
        int s = wsum[lane];
        #pragma unroll
        for (int d = 1; d < 16; d <<= 1) {
            int y = __shfl_up(s, d, 64);
            if (lane >= d) s += y;
        }
        wsum[lane] = s;
    }
    __syncthreads();
    int wpre = wid ? wsum[wid - 1] : 0;
    if (tid < SCAN_NBLK) bsum[tid] = x - v + wpre;
}

__global__ void fill_kernel(const int* __restrict__ s0, const int* __restrict__ d0,
                            const int* __restrict__ s1, const int* __restrict__ d1,
                            const int* __restrict__ s2, const int* __restrict__ d2,
                            int* __restrict__ cur, const int* __restrict__ bsum,
                            int* __restrict__ eidx) {
    int i = blockIdx.x * blockDim.x + threadIdx.x;
    if (i >= 3 * N_EDGES) return;
    int r = i / N_EDGES;
    int e = i - r * N_EDGES;
    const int* s = (r == 0) ? s0 : (r == 1) ? s1 : s2;
    const int* d = (r == 0) ? d0 : (r == 1) ? d1 : d2;
    int x = r * N_NODES + d[e];
    int p = atomicAdd(&cur[x], 1) + bsum[x >> 10];
    eidx[p] = s[e];
}

// ---------------- per-(relation,node) mean aggregation (MLP version) ----------------
// one wave per (r,n); lane-parallel eidx prefetch + shfl broadcast + 8-deep gathers
__global__ void agg_kernel(const unsigned short* __restrict__ fb, const int* __restrict__ off,
                           const int* __restrict__ cnt, const int* __restrict__ bsum,
                           const int* __restrict__ eidx, unsigned short* __restrict__ agg) {
    int wid = (blockIdx.x * blockDim.x + threadIdx.x) >> 6;
    int lane = threadIdx.x & 63;
    if (wid >= SCAN_N) return;
    int r = wid / N_NODES;
    int n = wid - r * N_NODES;
    int start = off[wid] + bsum[wid >> 10];
    int deg = cnt[wid];
    float4 acc = make_float4(0.f, 0.f, 0.f, 0.f);
    const unsigned short* fbl = fb + lane * 4;
    for (int base = 0; base < deg; base += 64) {
        int m = min(deg - base, 64);
        int e = (lane < m) ? eidx[start + base + lane] : 0;
        int j = 0;
        for (; j + 7 < m; j += 8) {
            int t0 = __shfl(e, j + 0), t1 = __shfl(e, j + 1), t2 = __shfl(e, j + 2), t3 = __shfl(e, j + 3);
            int t4 = __shfl(e, j + 4), t5 = __shfl(e, j + 5), t6 = __shfl(e, j + 6), t7 = __shfl(e, j + 7);
            ushort4 v0 = *(const ushort4*)(fbl + (size_t)t0 * D);
            ushort4 v1 = *(const ushort4*)(fbl + (size_t)t1 * D);
            ushort4 v2 = *(const ushort4*)(fbl + (size_t)t2 * D);
            ushort4 v3 = *(const ushort4*)(fbl + (size_t)t3 * D);
            ushort4 v4 = *(const ushort4*)(fbl + (size_t)t4 * D);
            ushort4 v5 = *(const ushort4*)(fbl + (size_t)t5 * D);
            ushort4 v6 = *(const ushort4*)(fbl + (size_t)t6 * D);
            ushort4 v7 = *(const ushort4*)(fbl + (size_t)t7 * D);
            acc.x += ((bf2f(v0.x) + bf2f(v1.x)) + (bf2f(v2.x) + bf2f(v3.x))) + ((bf2f(v4.x) + bf2f(v5.x)) + (bf2f(v6.x) + bf2f(v7.x)));
            acc.y += ((bf2f(v0.y) + bf2f(v1.y)) + (bf2f(v2.y) + bf2f(v3.y))) + ((bf2f(v4.y) + bf2f(v5.y)) + (bf2f(v6.y) + bf2f(v7.y)));
            acc.z += ((bf2f(v0.z) + bf2f(v1.z)) + (bf2f(v2.z) + bf2f(v3.z))) + ((bf2f(v4.z) + bf2f(v5.z)) + (bf2f(v6.z) + bf2f(v7.z)));
            acc.w += ((bf2f(v0.w) + bf2f(v1.w)) + (bf2f(v2.w) + bf2f(v3.w))) + ((bf2f(v4.w) + bf2f(v5.w)) + (bf2f(v6.w) + bf2f(v7.w)));
        }
        for (; j < m; ++j) {
            int t = __shfl(e, j);
            ushort4 v = *(const ushort4*)(fbl + (size_t)t * D);
            acc.x += bf2f(v.x); acc.y += bf2f(v.y); acc.z += bf2f(v.z); acc.w += bf2f(v.w);
        }
    }
    float sc = (deg > 0) ? 1.0f / (float)deg : 0.0f;
    ushort4 pk;
    pk.x = f2bf(acc.x * sc);
    pk.y = f2bf(acc.y * sc);
    pk.z = f2bf(acc.z * sc);
    pk.w = f2bf(acc.w * sc);
    *(ushort4*)(agg + (((size_t)n * 3 + r) * D) + lane * 4) = pk;
}

// ---------------- fused GEMM: out = relu( A[50000][768] @ B[768][256] + masked biases ) ----------------
// T3-minimum 2-phase: double-buffered LDS, prefetch next K-tile before computing current.
// Bank-conflict fix: seg' = seg ^ ((row>>1)&3) — linear LDS dest, inverse-swizzled global
// source, swizzled ds_read (both-sides-or-neither).
__global__ __launch_bounds__(256) void gemm_kernel(
    const unsigned short* __restrict__ A, const unsigned short* __restrict__ BT,
    const int* __restrict__ cnt,
    const float* __restrict__ b0, const float* __restrict__ b1, const float* __restrict__ b2,
    float* __restrict__ out) {
    __shared__ __bf16 Asl[2][M_TILE][BK];   // 2 x 8 KB
    __shared__ __bf16 Bsl[2][N_TILE][BK];   // 2 x 8 KB
    int tid = threadIdx.x;
    int lane = tid & 63, w = tid >> 6;
    int wr = w >> 1, wc = w & 1;
    int m0 = blockIdx.y * M_TILE;
    int c0 = blockIdx.x * N_TILE;
    f32x4 acc[4][4] = {};

    auto stage = [&](int kt, int b) {
        #pragma unroll
        for (int it = 0; it < 2; ++it) {
            int s = it * 256 + w * 64 + lane;            // 16B slot 0..511, linear LDS dest
            int row = s >> 2;
            int segg = (s & 3) ^ ((row >> 1) & 3);       // inverse-swizzled global seg
            int gm = m0 + row; if (gm >= N_NODES) gm = N_NODES - 1;  // M-tail clamp
            gload16(A + (size_t)gm * K_TOT + kt * BK + segg * 8,
                    &Asl[b][0][0] + (size_t)s * 8);
            gload16(BT + (size_t)(c0 + row) * K_TOT + kt * BK + segg * 8,
                    &Bsl[b][0][0] + (size_t)s * 8);
        }
    };

    stage(0, 0);
    __syncthreads();
    int buf = 0;
    for (int kt = 0; kt < NKT; ++kt) {
        if (kt + 1 < NKT) stage(kt + 1, buf ^ 1);        // prefetch next tile first
        int q = lane >> 4;
        int rr = lane & 15;
        bf16x8 af[4], bfr[4];
        #pragma unroll
        for (int mf = 0; mf < 4; ++mf) {
            int row = wr * 64 + mf * 16 + rr;
            af[mf] = *(const bf16x8*)&Asl[buf][row][(q ^ ((row >> 1) & 3)) * 8];
        }
        #pragma unroll
        for (int nf = 0; nf < 4; ++nf) {
            int row = wc * 64 + nf * 16 + rr;
            bfr[nf] = *(const bf16x8*)&Bsl[buf][row][(q ^ ((row >> 1) & 3)) * 8];
        }
        #pragma unroll
        for (int mf = 0; mf < 4; ++mf)
            #pragma unroll
            for (int nf = 0; nf < 4; ++nf)
                acc[mf][nf] = __builtin_amdgcn_mfma_f32_16x16x32_bf16(af[mf], bfr[nf], acc[mf][nf], 0, 0, 0);
        __syncthreads();                                  // drains vmcnt: next tile staged
        buf ^= 1;
    }

    // epilogue: masked biases + relu; C/D layout: col = lane&15, row = (lane>>4)*4 + reg
    #pragma unroll
    for (int mf = 0; mf < 4; ++mf) {
        #pragma unroll
        for (int nf = 0; nf < 4; ++nf) {
            int col = c0 + wc * 64 + nf * 16 + (lane & 15);
            #pragma unroll
            for (int reg = 0; reg < 4; ++reg) {
                int row = m0 + wr * 64 + mf * 16 + ((lane >> 4) * 4) + reg;
                if (row < N_NODES) {
                    float v = acc[mf][nf][reg];
                    if (cnt[row] > 0)               v += b0[col];
                    if (cnt[N_NODES + row] > 0)     v += b1[col];
                    if (cnt[2 * N_NODES + row] > 0) v += b2[col];
                    out[(size_t)row * D + col] = fmaxf(v, 0.0f);
                }
            }
        }
    }
}

extern "C" void kernel_launch(void* const* d_in, const int* in_sizes, int n_in,
                              void* d_out, int out_size, void* d_ws, size_t ws_size,
                              hipStream_t stream) {
    const float* feat = (const float*)d_in[0];
    const int* src0 = (const int*)d_in[1];
    const int* dst0 = (const int*)d_in[2];
    const int* src1 = (const int*)d_in[3];
    const int* dst1 = (const int*)d_in[4];
    const int* src2 = (const int*)d_in[5];
    const int* dst2 = (const int*)d_in[6];
    const float* W0 = (const float*)d_in[7];
    const float* b0 = (const float*)d_in[8];
    const float* W1 = (const float*)d_in[9];
    const float* b1 = (const float*)d_in[10];
    const float* W2 = (const float*)d_in[11];
    const float* b2 = (const float*)d_in[12];
    float* out = (float*)d_out;

    char* ws = (char*)d_ws;
    size_t o = 0;
    auto alloc = [&](size_t bytes) {
        size_t r = o;
        o += (bytes + 255) & ~(size_t)255;
        return r;
    };
    int* cnt            = (int*)(ws + alloc((size_t)SCAN_N * 4));
    int* off            = (int*)(ws + alloc((size_t)SCAN_N * 4));
    int* cur            = (int*)(ws + alloc((size_t)SCAN_N * 4));
    int* bsum           = (int*)(ws + alloc((size_t)SCAN_NBLK * 4));
    int* eidx           = (int*)(ws + alloc(3ull * N_EDGES * 4));
    unsigned short* WT  = (unsigned short*)(ws + alloc((size_t)D * K_TOT * 2));
    unsigned short* fb  = (unsigned short*)(ws + alloc((size_t)N_NODES * D * 2));
    unsigned short* agg = (unsigned short*)(ws + alloc(3ull * N_NODES * D * 2));

    prep_kernel<<<(N_NODES * D / 4 + 255) / 256, 256, 0, stream>>>(feat, fb, W0, W1, W2, WT, cnt);
    count_kernel<<<(3 * N_EDGES + 255) / 256, 256, 0, stream>>>(dst0, dst1, dst2, cnt);
    scan1_kernel<<<SCAN_NBLK, 1024, 0, stream>>>(cnt, off, cur, bsum);
    scan2_kernel<<<1, 1024, 0, stream>>>(bsum);
    fill_kernel<<<(3 * N_EDGES + 255) / 256, 256, 0, stream>>>(src0, dst0, src1, dst1, src2, dst2, cur, bsum, eidx);
    agg_kernel<<<(SCAN_N * 64) / 256 + 1, 256, 0, stream>>>(fb, off, cnt, bsum, eidx, agg);
    dim3 g(D / N_TILE, (N_NODES + M_TILE - 1) / M_TILE);
    gemm_kernel<<<g, 256, 0, stream>>>(agg, WT, cnt, b0, b1, b2, out);
}